// Round 7
// baseline (441.209 us; speedup 1.0000x reference)
//
#include <hip/hip_runtime.h>
#include <hip/hip_bf16.h>
#include <stdint.h>

#define N_NODES 100000
#define N_ROOTS 4096
#define N_EDGES 1600000

#define BUCKET_BITS 9
#define BUCKET_NODES 512
#define NBUCK ((N_NODES + BUCKET_NODES - 1) / BUCKET_NODES)  // 196
#define BUCK_CAP 12288
#define BIN_CHUNK 4096
#define NB_BIN ((N_EDGES + BIN_CHUNK - 1) / BIN_CHUNK)       // 391
#define SRCS_CAP (N_EDGES + N_NODES * 8 + 256)

#define ROWSP (N_NODES + 8)          // rows per slab incl. zero row at N_NODES
#define SLABW ((size_t)ROWSP * 32)   // ushorts per 32-col slab

typedef __attribute__((ext_vector_type(4))) float f32x4;
typedef __attribute__((ext_vector_type(8))) short bf16x8;

__device__ __forceinline__ ushort f2b(float f) {
  uint32_t u = __float_as_uint(f);
  uint32_t r = (u + 0x7FFFu + ((u >> 16) & 1u)) >> 16;  // RNE
  return (ushort)r;
}

// f32 row-major [n][128] -> bf16 sliced [4 slabs][ROWSP][32]
__global__ void k_cvt_sliced(const float* __restrict__ in, ushort* __restrict__ out, int n) {
  int g = blockIdx.x * blockDim.x + threadIdx.x;  // (node, 8-col group)
  int stride = gridDim.x * blockDim.x;
  int total = n * 16;
  for (; g < total; g += stride) {
    int node = g >> 4, cg = g & 15;
    const float4* p = (const float4*)(in + (size_t)node * 128 + cg * 8);
    float4 v0 = p[0], v1 = p[1];
    uint32_t w0 = (uint32_t)f2b(v0.x) | ((uint32_t)f2b(v0.y) << 16);
    uint32_t w1 = (uint32_t)f2b(v0.z) | ((uint32_t)f2b(v0.w) << 16);
    uint32_t w2 = (uint32_t)f2b(v1.x) | ((uint32_t)f2b(v1.y) << 16);
    uint32_t w3 = (uint32_t)f2b(v1.z) | ((uint32_t)f2b(v1.w) << 16);
    int slab = cg >> 2, in8 = (cg & 3) * 8;
    *(uint4*)(out + (size_t)slab * SLABW + (size_t)node * 32 + in8) = make_uint4(w0, w1, w2, w3);
  }
}

// ---- bucketed CSR build (R6, unchanged) ----
__global__ __launch_bounds__(256) void k_bin(const int* __restrict__ srcA, const int* __restrict__ dstA,
                                             int* __restrict__ bucket_cnt, int* __restrict__ binned) {
  __shared__ int hist[NBUCK];
  __shared__ int lscan[NBUCK];
  __shared__ int rsv[NBUCK];
  __shared__ int lpos[NBUCK];
  __shared__ int ws[4];
  __shared__ int2 ent[BIN_CHUNK];
  int t = threadIdx.x;
  int e0 = blockIdx.x * BIN_CHUNK;
  int cnt = min(BIN_CHUNK, N_EDGES - e0);
  for (int i = t; i < NBUCK; i += 256) hist[i] = 0;
  __syncthreads();
  for (int j = t; j < cnt; j += 256) atomicAdd(&hist[dstA[e0 + j] >> BUCKET_BITS], 1);
  __syncthreads();
  {
    int lane = t & 63, wv = t >> 6;
    int v = (t < NBUCK) ? hist[t] : 0;
    int inc = v;
    for (int d = 1; d < 64; d <<= 1) { int x = __shfl_up(inc, d); if (lane >= d) inc += x; }
    if (lane == 63) ws[wv] = inc;
    __syncthreads();
    int wbase = 0;
    for (int k = 0; k < wv; ++k) wbase += ws[k];
    if (t < NBUCK) {
      int excl = wbase + inc - v;
      lscan[t] = excl;
      lpos[t] = excl;
      rsv[t] = (v > 0) ? atomicAdd(&bucket_cnt[t], v) : 0;
    }
  }
  __syncthreads();
  for (int j = t; j < cnt; j += 256) {
    int s = srcA[e0 + j], d = dstA[e0 + j];
    int p = atomicAdd(&lpos[d >> BUCKET_BITS], 1);
    ent[p] = make_int2(s, d);
  }
  __syncthreads();
  for (int j = t; j < cnt; j += 256) {
    int2 E = ent[j];
    int b = E.y >> BUCKET_BITS;
    int pos = rsv[b] + (j - lscan[b]);
    if (pos < BUCK_CAP)
      binned[b * BUCK_CAP + pos] = (E.x << BUCKET_BITS) | (E.y & (BUCKET_NODES - 1));
  }
}

__global__ __launch_bounds__(512) void k_deg(const int* __restrict__ binned,
                                             const int* __restrict__ bucket_cnt,
                                             int* __restrict__ degg, int* __restrict__ pad_cnt) {
  __shared__ int deg[BUCKET_NODES];
  __shared__ int ws[8];
  int b = blockIdx.x, t = threadIdx.x;
  int cnt = min(bucket_cnt[b], BUCK_CAP);
  deg[t] = 0;
  __syncthreads();
  for (int j = t; j < cnt; j += 512) atomicAdd(&deg[binned[b * BUCK_CAP + j] & (BUCKET_NODES - 1)], 1);
  __syncthreads();
  int n0 = b * BUCKET_NODES;
  int nn = min(BUCKET_NODES, N_NODES - n0);
  int d = (t < nn) ? deg[t] : 0;
  if (t < nn) degg[n0 + t] = d;
  int dp = (d + 7) & ~7;
  int lane = t & 63, wv = t >> 6;
  for (int q = 1; q < 64; q <<= 1) dp += __shfl_xor(dp, q);
  if (lane == 0) ws[wv] = dp;
  __syncthreads();
  if (t == 0) {
    int tot = 0;
    for (int k = 0; k < 8; ++k) tot += ws[k];
    pad_cnt[b] = tot;
  }
}

__global__ __launch_bounds__(256) void k_bucket_scan(const int* __restrict__ pad_cnt,
                                                     int* __restrict__ bucket_base,
                                                     int* __restrict__ off_last) {
  __shared__ int ws[4];
  int t = threadIdx.x;
  int lane = t & 63, wv = t >> 6;
  int v = (t < NBUCK) ? pad_cnt[t] : 0;
  int inc = v;
  for (int d = 1; d < 64; d <<= 1) { int x = __shfl_up(inc, d); if (lane >= d) inc += x; }
  if (lane == 63) ws[wv] = inc;
  __syncthreads();
  int wbase = 0;
  for (int k = 0; k < wv; ++k) wbase += ws[k];
  if (t < NBUCK) bucket_base[t] = wbase + inc - v;
  if (t == NBUCK - 1) *off_last = wbase + inc;
}

__global__ __launch_bounds__(512) void k_csr(const int* __restrict__ binned,
                                             const int* __restrict__ bucket_cnt,
                                             const int* __restrict__ bucket_base,
                                             const int* __restrict__ degg,
                                             int* __restrict__ off, int* __restrict__ srcs) {
  __shared__ int sAb[BUCKET_NODES];
  __shared__ int sBb[BUCKET_NODES];
  __shared__ int pos[BUCKET_NODES];
  __shared__ int dreal[BUCKET_NODES];
  __shared__ int epk[BUCK_CAP];
  int b = blockIdx.x;
  int t = threadIdx.x;
  int cnt = min(bucket_cnt[b], BUCK_CAP);
  int gbase = bucket_base[b];
  int n0 = b * BUCKET_NODES;
  int nn = min(BUCKET_NODES, N_NODES - n0);
  int d = (t < nn) ? degg[n0 + t] : 0;
  dreal[t] = d;
  int dp = (d + 7) & ~7;
  int* sA = sAb; int* sB = sBb;
  sA[t] = dp;
  __syncthreads();
  for (int q = 1; q < 512; q <<= 1) {
    int x = sA[t];
    if (t >= q) x += sA[t - q];
    sB[t] = x;
    __syncthreads();
    int* tp = sA; sA = sB; sB = tp;
  }
  int ex = sA[t] - dp;
  pos[t] = ex;
  if (t < nn) off[n0 + t] = gbase + ex;
  __syncthreads();
  for (int j = t; j < cnt; j += 512) epk[j] = binned[b * BUCK_CAP + j];
  __syncthreads();
  for (int j = t; j < cnt; j += 512) {
    int p = epk[j];
    int q = atomicAdd(&pos[p & (BUCKET_NODES - 1)], 1);
    srcs[gbase + q] = p >> BUCKET_BITS;
  }
  __syncthreads();
  int start = sA[t] - dp;
  int fill0 = start + dreal[t];
  int fill1 = start + ((dreal[t] + 7) & ~7);
  for (int q = fill0; q < fill1; ++q) srcs[gbase + q] = N_NODES;  // zero-row dummy
}

// sliced GEMM: out[slab][row][32](bf16) = A @ W; A sliced (A0|A1 at k=128, optional relu on A0)
__global__ __launch_bounds__(256) void k_gemm(
    const ushort* __restrict__ A0, const ushort* __restrict__ A1,
    const float* __restrict__ W, ushort* __restrict__ out, int n, int K, int relu0)
{
  extern __shared__ char smem[];  // W^T swizzled: (k,c) -> byte c*2K + ((2k)^((c&7)<<4))
  const int KC = K * 128;
  for (int idx = threadIdx.x; idx < KC; idx += 256) {
    int k = idx >> 7, c = idx & 127;
    ushort b = f2b(W[idx]);
    *(ushort*)(smem + c * (K * 2) + ((k * 2) ^ ((c & 7) << 4))) = b;
  }
  __syncthreads();

  int lane = threadIdx.x & 63;
  int wv = threadIdx.x >> 6;
  int rowBase = blockIdx.x * 128 + wv * 32;
  int rl = lane & 15;
  int kh = lane >> 4;
  int r0 = rowBase + rl, r1 = r0 + 16;
  int r0c = min(r0, n - 1), r1c = min(r1, n - 1);

  f32x4 acc[2][8];
#pragma unroll
  for (int i = 0; i < 2; ++i)
#pragma unroll
    for (int j = 0; j < 8; ++j)
      acc[i][j] = (f32x4){0.f, 0.f, 0.f, 0.f};

  int nks = K >> 5;
  for (int ks = 0; ks < nks; ++ks) {
    const ushort* Asrc = (ks < 4) ? A0 : A1;
    int kof = ((ks & 3) << 5) + (kh << 3);       // col 0..127 within that matrix
    const ushort* ap = Asrc + (size_t)(kof >> 5) * SLABW + (kof & 31);
    bf16x8 a0 = *(const bf16x8*)(ap + (size_t)r0c * 32);
    bf16x8 a1 = *(const bf16x8*)(ap + (size_t)r1c * 32);
    if (relu0 && ks < 4) {
#pragma unroll
      for (int q = 0; q < 8; ++q) {
        short v0 = a0[q]; a0[q] = (short)(v0 & ~(v0 >> 15));
        short v1 = a1[q]; a1[q] = (short)(v1 & ~(v1 >> 15));
      }
    }
    int kk = (ks << 5) + (kh << 3);
#pragma unroll
    for (int ct = 0; ct < 8; ++ct) {
      int col = (ct << 4) + rl;
      bf16x8 b = *(const bf16x8*)(smem + col * (K * 2) + ((kk * 2) ^ ((col & 7) << 4)));
      acc[0][ct] = __builtin_amdgcn_mfma_f32_16x16x32_bf16(a0, b, acc[0][ct], 0, 0, 0);
      acc[1][ct] = __builtin_amdgcn_mfma_f32_16x16x32_bf16(a1, b, acc[1][ct], 0, 0, 0);
    }
  }
#pragma unroll
  for (int ri = 0; ri < 2; ++ri)
#pragma unroll
    for (int ct = 0; ct < 8; ++ct) {
      size_t sb = (size_t)(ct >> 1) * SLABW;
      int incol = ((ct & 1) << 4) + rl;
#pragma unroll
      for (int j = 0; j < 4; ++j) {
        int row = rowBase + ri * 16 + kh * 4 + j;
        if (row < n) out[sb + (size_t)row * 32 + incol] = f2b(acc[ri][ct][j]);
      }
    }
}

// sliced segment-sum: slice = (blockIdx%8)>>1 (XCD-pair pinned), 32-col slab, 64B/edge-gather.
// wave: lane=(ns 0..3, cd 0..15) -> 4 nodes/instr, per-lane private accumulate, no shuffles.
__global__ __launch_bounds__(256) void k_aggr(
    const ushort* __restrict__ hlin_s, const int* __restrict__ off, const int* __restrict__ srcs,
    const float* __restrict__ bias, ushort* __restrict__ hbf_s, float* __restrict__ outf,
    int first, int last)
{
  int b = blockIdx.x;
  int xcd = b & 7;
  int slice = xcd >> 1;
  int half = xcd & 1;
  int chunk = b >> 3;
  int lane = threadIdx.x & 63, wv = threadIdx.x >> 6;
  int ns = lane >> 4, cd = lane & 15;
  int node = chunk * 32 + half * 16 + wv * 4 + ns;
  bool valid = node < N_NODES;
  int s = 0, deg = 0;
  if (valid) { s = off[node]; deg = off[node + 1] - s; }
  int dmax = deg;
  dmax = max(dmax, __shfl_xor(dmax, 16));
  dmax = max(dmax, __shfl_xor(dmax, 32));
  const uint32_t* slab = (const uint32_t*)hlin_s + (size_t)slice * (SLABW / 2);
  float a0 = 0.f, a1 = 0.f;
  for (int j = 0; j < dmax; j += 8) {
    bool live = (j < deg);
    int idx[8];
#pragma unroll
    for (int q = 0; q < 8; ++q) {
      int ii = srcs[s + j + q];
      idx[q] = live ? ii : N_NODES;
    }
    uint32_t u[8];
#pragma unroll
    for (int q = 0; q < 8; ++q) u[q] = slab[(size_t)idx[q] * 16 + cd];
#pragma unroll
    for (int q = 0; q < 8; ++q) {
      a0 += __uint_as_float(u[q] << 16);
      a1 += __uint_as_float(u[q] & 0xFFFF0000u);
    }
  }
  if (!valid) return;
  float2 bv = ((const float2*)bias)[slice * 16 + cd];
  uint32_t* hb = (uint32_t*)hbf_s + (size_t)slice * (SLABW / 2);
  size_t hi = (size_t)node * 16 + cd;
  float h0, h1;
  if (first) {
    h0 = a0 + bv.x; h1 = a1 + bv.y;
  } else {
    uint32_t up = hb[hi];
    h0 = __uint_as_float(up << 16) + a0 + bv.x;
    h1 = __uint_as_float(up & 0xFFFF0000u) + a1 + bv.y;
  }
  if (last) {
    if (node < N_ROOTS)
      *(float2*)(outf + (size_t)node * 128 + slice * 32 + cd * 2) = make_float2(h0, h1);
  } else {
    hb[hi] = (uint32_t)f2b(h0) | ((uint32_t)f2b(h1) << 16);
  }
}

extern "C" void kernel_launch(void* const* d_in, const int* in_sizes, int n_in,
                              void* d_out, int out_size, void* d_ws, size_t ws_size,
                              hipStream_t stream) {
  const float* x = (const float*)d_in[0];
  const int* ei  = (const int*)d_in[1];
  const int* src = ei;
  const int* dst = ei + N_EDGES;
  const float* Wp[4] = {(const float*)d_in[4], (const float*)d_in[6],
                        (const float*)d_in[8], (const float*)d_in[10]};
  const float* bp[4] = {(const float*)d_in[5], (const float*)d_in[7],
                        (const float*)d_in[9], (const float*)d_in[11]};

  char* w = (char*)d_ws;
  auto alloc = [&](size_t bytes) {
    char* p = w;
    w += (bytes + 255) & ~(size_t)255;
    return p;
  };
  ushort* xs       = (ushort*)alloc(4 * SLABW * 2);   // x, sliced
  ushort* hbf_s    = (ushort*)alloc(4 * SLABW * 2);   // running h, sliced
  ushort* hlin_s   = (ushort*)alloc(4 * SLABW * 2);   // per-layer messages, sliced
  int*    off      = (int*)   alloc((size_t)(N_NODES + 1) * 4);
  int*    srcs     = (int*)   alloc((size_t)SRCS_CAP * 4);
  int*    binned   = (int*)   alloc((size_t)NBUCK * BUCK_CAP * 4);
  int*    degg     = (int*)   alloc((size_t)N_NODES * 4);
  int*    bucket_cnt  = (int*)alloc((size_t)NBUCK * 4);
  int*    pad_cnt     = (int*)alloc((size_t)NBUCK * 4);
  int*    bucket_base = (int*)alloc((size_t)(NBUCK + 1) * 4);
  if ((size_t)(w - (char*)d_ws) > ws_size) return;

  hipMemsetAsync(bucket_cnt, 0, (size_t)NBUCK * 4, stream);
  // zero row (node N_NODES) in each hlin slab, for dummy/padded edges
  for (int sl = 0; sl < 4; ++sl)
    hipMemsetAsync(hlin_s + (size_t)sl * SLABW + (size_t)N_NODES * 32, 0, 64, stream);
  k_cvt_sliced<<<2048, 256, 0, stream>>>(x, xs, N_NODES);
  k_bin<<<NB_BIN, 256, 0, stream>>>(src, dst, bucket_cnt, binned);
  k_deg<<<NBUCK, 512, 0, stream>>>(binned, bucket_cnt, degg, pad_cnt);
  k_bucket_scan<<<1, 256, 0, stream>>>(pad_cnt, bucket_base, off + N_NODES);
  k_csr<<<NBUCK, 512, 0, stream>>>(binned, bucket_cnt, bucket_base, degg, off, srcs);

  int gblocks = (N_NODES + 127) / 128;
  int ablocks = ((N_NODES + 31) / 32) * 8;   // chunk x (4 slices x 2 halves), xcd = blockIdx%8
  // layer 0
  k_gemm<<<gblocks, 256, 128 * 128 * 2, stream>>>(xs, xs, Wp[0], hlin_s, N_NODES, 128, 0);
  k_aggr<<<ablocks, 256, 0, stream>>>(hlin_s, off, srcs, bp[0], hbf_s, (float*)d_out, 1, 0);
  // layers 1..3
  for (int l = 1; l < 4; ++l) {
    k_gemm<<<gblocks, 256, 256 * 128 * 2, stream>>>(hbf_s, xs, Wp[l], hlin_s, N_NODES, 256, 1);
    k_aggr<<<ablocks, 256, 0, stream>>>(hlin_s, off, srcs, bp[l], hbf_s, (float*)d_out,
                                        0, (l == 3) ? 1 : 0);
  }
}

// Round 8
// 356.055 us; speedup vs baseline: 1.2392x; 1.2392x over previous
//
#include <hip/hip_runtime.h>
#include <hip/hip_bf16.h>
#include <stdint.h>

#define N_NODES 100000
#define N_EDGES 1600000
#define FEAT 128
#define EMB 128
#define N_ROOTS 4096

#define BUCKET_BITS 9
#define BUCKET_NODES 512
#define NBUCK ((N_NODES + BUCKET_NODES - 1) / BUCKET_NODES)  // 196
#define BUCK_CAP 12288
#define BIN_CHUNK 4096
#define NB_BIN ((N_EDGES + BIN_CHUNK - 1) / BIN_CHUNK)       // 391
#define SRCS_CAP (N_EDGES + N_NODES * 8 + 256)

typedef __attribute__((ext_vector_type(4))) float f32x4;
typedef __attribute__((ext_vector_type(8))) short bf16x8;

__device__ __forceinline__ ushort f2b(float f) {
  uint32_t u = __float_as_uint(f);
  uint32_t r = (u + 0x7FFFu + ((u >> 16) & 1u)) >> 16;  // RNE
  return (ushort)r;
}

__global__ void k_cvt_bf16(const float* __restrict__ in, ushort* __restrict__ out, int n4) {
  int i = blockIdx.x * blockDim.x + threadIdx.x;
  int stride = gridDim.x * blockDim.x;
  for (; i < n4; i += stride) {
    float4 v = ((const float4*)in)[i];
    ushort4 o;
    o.x = f2b(v.x); o.y = f2b(v.y); o.z = f2b(v.z); o.w = f2b(v.w);
    ((ushort4*)out)[i] = o;
  }
}

// ---- bucketed CSR build, padded to 8-edge multiples per node (R6) ----
__global__ __launch_bounds__(256) void k_bin(const int* __restrict__ srcA, const int* __restrict__ dstA,
                                             int* __restrict__ bucket_cnt, int* __restrict__ binned) {
  __shared__ int hist[NBUCK];
  __shared__ int lscan[NBUCK];
  __shared__ int rsv[NBUCK];
  __shared__ int lpos[NBUCK];
  __shared__ int ws[4];
  __shared__ int2 ent[BIN_CHUNK];
  int t = threadIdx.x;
  int e0 = blockIdx.x * BIN_CHUNK;
  int cnt = min(BIN_CHUNK, N_EDGES - e0);
  for (int i = t; i < NBUCK; i += 256) hist[i] = 0;
  __syncthreads();
  for (int j = t; j < cnt; j += 256) atomicAdd(&hist[dstA[e0 + j] >> BUCKET_BITS], 1);
  __syncthreads();
  {
    int lane = t & 63, wv = t >> 6;
    int v = (t < NBUCK) ? hist[t] : 0;
    int inc = v;
    for (int d = 1; d < 64; d <<= 1) { int x = __shfl_up(inc, d); if (lane >= d) inc += x; }
    if (lane == 63) ws[wv] = inc;
    __syncthreads();
    int wbase = 0;
    for (int k = 0; k < wv; ++k) wbase += ws[k];
    if (t < NBUCK) {
      int excl = wbase + inc - v;
      lscan[t] = excl;
      lpos[t] = excl;
      rsv[t] = (v > 0) ? atomicAdd(&bucket_cnt[t], v) : 0;
    }
  }
  __syncthreads();
  for (int j = t; j < cnt; j += 256) {
    int s = srcA[e0 + j], d = dstA[e0 + j];
    int p = atomicAdd(&lpos[d >> BUCKET_BITS], 1);
    ent[p] = make_int2(s, d);
  }
  __syncthreads();
  for (int j = t; j < cnt; j += 256) {
    int2 E = ent[j];
    int b = E.y >> BUCKET_BITS;
    int pos = rsv[b] + (j - lscan[b]);
    if (pos < BUCK_CAP)
      binned[b * BUCK_CAP + pos] = (E.x << BUCKET_BITS) | (E.y & (BUCKET_NODES - 1));
  }
}

__global__ __launch_bounds__(512) void k_deg(const int* __restrict__ binned,
                                             const int* __restrict__ bucket_cnt,
                                             int* __restrict__ degg, int* __restrict__ pad_cnt) {
  __shared__ int deg[BUCKET_NODES];
  __shared__ int ws[8];
  int b = blockIdx.x, t = threadIdx.x;
  int cnt = min(bucket_cnt[b], BUCK_CAP);
  deg[t] = 0;
  __syncthreads();
  for (int j = t; j < cnt; j += 512) atomicAdd(&deg[binned[b * BUCK_CAP + j] & (BUCKET_NODES - 1)], 1);
  __syncthreads();
  int n0 = b * BUCKET_NODES;
  int nn = min(BUCKET_NODES, N_NODES - n0);
  int d = (t < nn) ? deg[t] : 0;
  if (t < nn) degg[n0 + t] = d;
  int dp = (d + 7) & ~7;
  int lane = t & 63, wv = t >> 6;
  for (int q = 1; q < 64; q <<= 1) dp += __shfl_xor(dp, q);
  if (lane == 0) ws[wv] = dp;
  __syncthreads();
  if (t == 0) {
    int tot = 0;
    for (int k = 0; k < 8; ++k) tot += ws[k];
    pad_cnt[b] = tot;
  }
}

__global__ __launch_bounds__(256) void k_bucket_scan(const int* __restrict__ pad_cnt,
                                                     int* __restrict__ bucket_base,
                                                     int* __restrict__ off_last) {
  __shared__ int ws[4];
  int t = threadIdx.x;
  int lane = t & 63, wv = t >> 6;
  int v = (t < NBUCK) ? pad_cnt[t] : 0;
  int inc = v;
  for (int d = 1; d < 64; d <<= 1) { int x = __shfl_up(inc, d); if (lane >= d) inc += x; }
  if (lane == 63) ws[wv] = inc;
  __syncthreads();
  int wbase = 0;
  for (int k = 0; k < wv; ++k) wbase += ws[k];
  if (t < NBUCK) bucket_base[t] = wbase + inc - v;
  if (t == NBUCK - 1) *off_last = wbase + inc;
}

__global__ __launch_bounds__(512) void k_csr(const int* __restrict__ binned,
                                             const int* __restrict__ bucket_cnt,
                                             const int* __restrict__ bucket_base,
                                             const int* __restrict__ degg,
                                             int* __restrict__ off, int* __restrict__ srcs) {
  __shared__ int sAb[BUCKET_NODES];
  __shared__ int sBb[BUCKET_NODES];
  __shared__ int pos[BUCKET_NODES];
  __shared__ int dreal[BUCKET_NODES];
  __shared__ int epk[BUCK_CAP];
  int b = blockIdx.x;
  int t = threadIdx.x;
  int cnt = min(bucket_cnt[b], BUCK_CAP);
  int gbase = bucket_base[b];
  int n0 = b * BUCKET_NODES;
  int nn = min(BUCKET_NODES, N_NODES - n0);
  int d = (t < nn) ? degg[n0 + t] : 0;
  dreal[t] = d;
  int dp = (d + 7) & ~7;
  int* sA = sAb; int* sB = sBb;
  sA[t] = dp;
  __syncthreads();
  for (int q = 1; q < 512; q <<= 1) {
    int x = sA[t];
    if (t >= q) x += sA[t - q];
    sB[t] = x;
    __syncthreads();
    int* tp = sA; sA = sB; sB = tp;
  }
  int ex = sA[t] - dp;
  pos[t] = ex;
  if (t < nn) off[n0 + t] = gbase + ex;
  __syncthreads();
  for (int j = t; j < cnt; j += 512) epk[j] = binned[b * BUCK_CAP + j];
  __syncthreads();
  for (int j = t; j < cnt; j += 512) {
    int p = epk[j];
    int q = atomicAdd(&pos[p & (BUCKET_NODES - 1)], 1);
    srcs[gbase + q] = p >> BUCKET_BITS;
  }
  __syncthreads();
  int start = sA[t] - dp;
  int fill0 = start + dreal[t];
  int fill1 = start + ((dreal[t] + 7) & ~7);
  for (int q = fill0; q < fill1; ++q) srcs[gbase + q] = N_NODES;  // zero-row dummy
}

// out[n][128](bf16) = A[n][K](bf16, A0|A1 split at k=128, optional relu on A0) @ W[K][128]
__global__ __launch_bounds__(256) void k_gemm(
    const ushort* __restrict__ A0, const ushort* __restrict__ A1,
    const float* __restrict__ W, ushort* __restrict__ out, int n, int K, int relu0)
{
  extern __shared__ char smem[];  // W^T swizzled: (k,c) -> byte c*2K + ((2k)^((c&7)<<4))
  const int KC = K * 128;
  for (int idx = threadIdx.x; idx < KC; idx += 256) {
    int k = idx >> 7, c = idx & 127;
    ushort b = f2b(W[idx]);
    *(ushort*)(smem + c * (K * 2) + ((k * 2) ^ ((c & 7) << 4))) = b;
  }
  __syncthreads();

  int lane = threadIdx.x & 63;
  int wv = threadIdx.x >> 6;
  int rowBase = blockIdx.x * 128 + wv * 32;
  int rl = lane & 15;
  int kh = lane >> 4;
  int r0 = rowBase + rl, r1 = r0 + 16;
  int r0c = min(r0, n - 1), r1c = min(r1, n - 1);

  f32x4 acc[2][8];
#pragma unroll
  for (int i = 0; i < 2; ++i)
#pragma unroll
    for (int j = 0; j < 8; ++j)
      acc[i][j] = (f32x4){0.f, 0.f, 0.f, 0.f};

  int nks = K >> 5;
  for (int ks = 0; ks < nks; ++ks) {
    const ushort* Asrc = (ks < 4) ? A0 : A1;
    int kof = ((ks & 3) << 5) + (kh << 3);
    bf16x8 a0 = *(const bf16x8*)(Asrc + (size_t)r0c * 128 + kof);
    bf16x8 a1 = *(const bf16x8*)(Asrc + (size_t)r1c * 128 + kof);
    if (relu0 && ks < 4) {
#pragma unroll
      for (int q = 0; q < 8; ++q) {
        short v0 = a0[q]; a0[q] = (short)(v0 & ~(v0 >> 15));
        short v1 = a1[q]; a1[q] = (short)(v1 & ~(v1 >> 15));
      }
    }
    int kk = (ks << 5) + (kh << 3);
#pragma unroll
    for (int ct = 0; ct < 8; ++ct) {
      int col = (ct << 4) + rl;
      bf16x8 b = *(const bf16x8*)(smem + col * (K * 2) + ((kk * 2) ^ ((col & 7) << 4)));
      acc[0][ct] = __builtin_amdgcn_mfma_f32_16x16x32_bf16(a0, b, acc[0][ct], 0, 0, 0);
      acc[1][ct] = __builtin_amdgcn_mfma_f32_16x16x32_bf16(a1, b, acc[1][ct], 0, 0, 0);
    }
  }
#pragma unroll
  for (int ri = 0; ri < 2; ++ri)
#pragma unroll
    for (int ct = 0; ct < 8; ++ct) {
      int col = (ct << 4) + rl;
#pragma unroll
      for (int j = 0; j < 4; ++j) {
        int row = rowBase + ri * 16 + kh * 4 + j;
        if (row < n) out[(size_t)row * 128 + col] = f2b(acc[ri][ct][j]);
      }
    }
}

// segment sum, padded CSR: 2 nodes/wave, 2 cols/lane, int4 index loads.
// Per interleaved step: 16 independent 256B row-gathers in flight.
__global__ __launch_bounds__(256) void k_aggr(
    const ushort* __restrict__ hlin, const int* __restrict__ off, const int* __restrict__ srcs,
    const float* __restrict__ bias, ushort* __restrict__ hbf, float* __restrict__ outf,
    int n, int first, int last)
{
  int wv = threadIdx.x >> 6;
  int lane = threadIdx.x & 63;
  int nodeA = blockIdx.x * 8 + wv * 2;
  if (nodeA >= n) return;
  int nodeB = nodeA + 1;
  bool hasB = nodeB < n;
  int sA = __builtin_amdgcn_readfirstlane(off[nodeA]);
  int eA = __builtin_amdgcn_readfirstlane(off[nodeA + 1]);
  int eB = hasB ? __builtin_amdgcn_readfirstlane(off[nodeB + 1]) : eA;
  // CSR is contiguous: off[nodeB] == eA
  float aA0 = 0.f, aA1 = 0.f, aB0 = 0.f, aB1 = 0.f;
  int ja = sA, jb = eA;
  // interleaved: 8 edges of A + 8 edges of B per step (16 gathers in flight)
  while (ja + 8 <= eA && jb + 8 <= eB) {
    int4 pa0 = *(const int4*)(srcs + ja), pa1 = *(const int4*)(srcs + ja + 4);
    int4 pb0 = *(const int4*)(srcs + jb), pb1 = *(const int4*)(srcs + jb + 4);
    uint32_t u[16];
    u[0]  = *(const uint32_t*)(hlin + (size_t)pa0.x * 128 + lane * 2);
    u[1]  = *(const uint32_t*)(hlin + (size_t)pa0.y * 128 + lane * 2);
    u[2]  = *(const uint32_t*)(hlin + (size_t)pa0.z * 128 + lane * 2);
    u[3]  = *(const uint32_t*)(hlin + (size_t)pa0.w * 128 + lane * 2);
    u[4]  = *(const uint32_t*)(hlin + (size_t)pa1.x * 128 + lane * 2);
    u[5]  = *(const uint32_t*)(hlin + (size_t)pa1.y * 128 + lane * 2);
    u[6]  = *(const uint32_t*)(hlin + (size_t)pa1.z * 128 + lane * 2);
    u[7]  = *(const uint32_t*)(hlin + (size_t)pa1.w * 128 + lane * 2);
    u[8]  = *(const uint32_t*)(hlin + (size_t)pb0.x * 128 + lane * 2);
    u[9]  = *(const uint32_t*)(hlin + (size_t)pb0.y * 128 + lane * 2);
    u[10] = *(const uint32_t*)(hlin + (size_t)pb0.z * 128 + lane * 2);
    u[11] = *(const uint32_t*)(hlin + (size_t)pb0.w * 128 + lane * 2);
    u[12] = *(const uint32_t*)(hlin + (size_t)pb1.x * 128 + lane * 2);
    u[13] = *(const uint32_t*)(hlin + (size_t)pb1.y * 128 + lane * 2);
    u[14] = *(const uint32_t*)(hlin + (size_t)pb1.z * 128 + lane * 2);
    u[15] = *(const uint32_t*)(hlin + (size_t)pb1.w * 128 + lane * 2);
#pragma unroll
    for (int q = 0; q < 8; ++q) {
      aA0 += __uint_as_float(u[q] << 16);
      aA1 += __uint_as_float(u[q] & 0xFFFF0000u);
    }
#pragma unroll
    for (int q = 8; q < 16; ++q) {
      aB0 += __uint_as_float(u[q] << 16);
      aB1 += __uint_as_float(u[q] & 0xFFFF0000u);
    }
    ja += 8; jb += 8;
  }
  // drain A
  for (; ja + 8 <= eA; ja += 8) {
    int4 p0 = *(const int4*)(srcs + ja), p1 = *(const int4*)(srcs + ja + 4);
    uint32_t u[8];
    u[0] = *(const uint32_t*)(hlin + (size_t)p0.x * 128 + lane * 2);
    u[1] = *(const uint32_t*)(hlin + (size_t)p0.y * 128 + lane * 2);
    u[2] = *(const uint32_t*)(hlin + (size_t)p0.z * 128 + lane * 2);
    u[3] = *(const uint32_t*)(hlin + (size_t)p0.w * 128 + lane * 2);
    u[4] = *(const uint32_t*)(hlin + (size_t)p1.x * 128 + lane * 2);
    u[5] = *(const uint32_t*)(hlin + (size_t)p1.y * 128 + lane * 2);
    u[6] = *(const uint32_t*)(hlin + (size_t)p1.z * 128 + lane * 2);
    u[7] = *(const uint32_t*)(hlin + (size_t)p1.w * 128 + lane * 2);
#pragma unroll
    for (int q = 0; q < 8; ++q) {
      aA0 += __uint_as_float(u[q] << 16);
      aA1 += __uint_as_float(u[q] & 0xFFFF0000u);
    }
  }
  // drain B
  for (; jb + 8 <= eB; jb += 8) {
    int4 p0 = *(const int4*)(srcs + jb), p1 = *(const int4*)(srcs + jb + 4);
    uint32_t u[8];
    u[0] = *(const uint32_t*)(hlin + (size_t)p0.x * 128 + lane * 2);
    u[1] = *(const uint32_t*)(hlin + (size_t)p0.y * 128 + lane * 2);
    u[2] = *(const uint32_t*)(hlin + (size_t)p0.z * 128 + lane * 2);
    u[3] = *(const uint32_t*)(hlin + (size_t)p0.w * 128 + lane * 2);
    u[4] = *(const uint32_t*)(hlin + (size_t)p1.x * 128 + lane * 2);
    u[5] = *(const uint32_t*)(hlin + (size_t)p1.y * 128 + lane * 2);
    u[6] = *(const uint32_t*)(hlin + (size_t)p1.z * 128 + lane * 2);
    u[7] = *(const uint32_t*)(hlin + (size_t)p1.w * 128 + lane * 2);
#pragma unroll
    for (int q = 0; q < 8; ++q) {
      aB0 += __uint_as_float(u[q] << 16);
      aB1 += __uint_as_float(u[q] & 0xFFFF0000u);
    }
  }
  float2 bv = ((const float2*)bias)[lane];
  // epilogue nodeA
  {
    size_t idx = (size_t)nodeA * 128 + lane * 2;
    float h0, h1;
    if (first) { h0 = aA0 + bv.x; h1 = aA1 + bv.y; }
    else {
      uint32_t up = *(const uint32_t*)(hbf + idx);
      h0 = __uint_as_float(up << 16) + aA0 + bv.x;
      h1 = __uint_as_float(up & 0xFFFF0000u) + aA1 + bv.y;
    }
    if (last) {
      *(float2*)(outf + idx) = make_float2(h0, h1);
    } else {
      ushort2 r; r.x = f2b(h0); r.y = f2b(h1);
      *(ushort2*)(hbf + idx) = r;
    }
  }
  if (hasB) {
    size_t idx = (size_t)nodeB * 128 + lane * 2;
    float h0, h1;
    if (first) { h0 = aB0 + bv.x; h1 = aB1 + bv.y; }
    else {
      uint32_t up = *(const uint32_t*)(hbf + idx);
      h0 = __uint_as_float(up << 16) + aB0 + bv.x;
      h1 = __uint_as_float(up & 0xFFFF0000u) + aB1 + bv.y;
    }
    if (last) {
      *(float2*)(outf + idx) = make_float2(h0, h1);
    } else {
      ushort2 r; r.x = f2b(h0); r.y = f2b(h1);
      *(ushort2*)(hbf + idx) = r;
    }
  }
}

extern "C" void kernel_launch(void* const* d_in, const int* in_sizes, int n_in,
                              void* d_out, int out_size, void* d_ws, size_t ws_size,
                              hipStream_t stream) {
  const float* x = (const float*)d_in[0];
  const int* ei  = (const int*)d_in[1];
  const int* src = ei;
  const int* dst = ei + N_EDGES;
  const float* Wp[4] = {(const float*)d_in[4], (const float*)d_in[6],
                        (const float*)d_in[8], (const float*)d_in[10]};
  const float* bp[4] = {(const float*)d_in[5], (const float*)d_in[7],
                        (const float*)d_in[9], (const float*)d_in[11]};

  char* w = (char*)d_ws;
  auto alloc = [&](size_t bytes) {
    char* p = w;
    w += (bytes + 255) & ~(size_t)255;
    return p;
  };
  ushort* x_bf     = (ushort*)alloc((size_t)N_NODES * 128 * 2);
  ushort* hbf      = (ushort*)alloc((size_t)N_NODES * 128 * 2);
  ushort* hlin     = (ushort*)alloc((size_t)(N_NODES + 8) * 128 * 2);  // +zero row
  int*    off      = (int*)   alloc((size_t)(N_NODES + 1) * 4);
  int*    srcs     = (int*)   alloc((size_t)SRCS_CAP * 4);
  int*    binned   = (int*)   alloc((size_t)NBUCK * BUCK_CAP * 4);
  int*    degg     = (int*)   alloc((size_t)N_NODES * 4);
  int*    bucket_cnt  = (int*)alloc((size_t)NBUCK * 4);
  int*    pad_cnt     = (int*)alloc((size_t)NBUCK * 4);
  int*    bucket_base = (int*)alloc((size_t)(NBUCK + 1) * 4);
  if ((size_t)(w - (char*)d_ws) > ws_size) return;

  hipMemsetAsync(bucket_cnt, 0, (size_t)NBUCK * 4, stream);
  hipMemsetAsync(hlin + (size_t)N_NODES * 128, 0, 256, stream);  // zero row for dummy edges
  k_cvt_bf16<<<2048, 256, 0, stream>>>(x, x_bf, N_NODES * 128 / 4);
  k_bin<<<NB_BIN, 256, 0, stream>>>(src, dst, bucket_cnt, binned);
  k_deg<<<NBUCK, 512, 0, stream>>>(binned, bucket_cnt, degg, pad_cnt);
  k_bucket_scan<<<1, 256, 0, stream>>>(pad_cnt, bucket_base, off + N_NODES);
  k_csr<<<NBUCK, 512, 0, stream>>>(binned, bucket_cnt, bucket_base, degg, off, srcs);

  int gblocks = (N_NODES + 127) / 128;
  int ablocks = (N_NODES + 7) / 8;
  // layer 0
  k_gemm<<<gblocks, 256, 128 * 128 * 2, stream>>>(x_bf, x_bf, Wp[0], hlin, N_NODES, 128, 0);
  k_aggr<<<ablocks, 256, 0, stream>>>(hlin, off, srcs, bp[0], hbf, (float*)d_out, N_NODES, 1, 0);
  // layers 1..2 (full), layer 3 aggregation only over root nodes 0..4095
  for (int l = 1; l < 4; ++l) {
    k_gemm<<<gblocks, 256, 256 * 128 * 2, stream>>>(hbf, x_bf, Wp[l], hlin, N_NODES, 256, 1);
    if (l < 3) {
      k_aggr<<<ablocks, 256, 0, stream>>>(hlin, off, srcs, bp[l], hbf, (float*)d_out,
                                          N_NODES, 0, 0);
    } else {
      k_aggr<<<(N_ROOTS + 7) / 8, 256, 0, stream>>>(hlin, off, srcs, bp[l], hbf, (float*)d_out,
                                                    N_ROOTS, 0, 1);
    }
  }
}